// Round 7
// baseline (190.716 us; speedup 1.0000x reference)
//
#include <hip/hip_runtime.h>

#define BB 64
#define JJ 24
#define TT 2048
#define NELEM (BB*JJ*6*TT)              // 18,874,368 floats
#define NVEL  ((long long)BB*JJ*6*(TT-1))
#define FOOT_BLOCKS 256
#define RBLOCKS 4608
#define NRT (RBLOCKS*256)               // 1,179,648 recon threads; 4 chunks each
#define NBLK (FOOT_BLOCKS + RBLOCKS)    // 4864 partial slots

__device__ __forceinline__ void block_reduce2f(float& a, float& b) {
    #pragma unroll
    for (int off = 32; off > 0; off >>= 1) {
        a += __shfl_down(a, off);
        b += __shfl_down(b, off);
    }
    __shared__ float sa[4], sb[4];
    const int lane = threadIdx.x & 63;
    const int wid  = threadIdx.x >> 6;
    if (lane == 0) { sa[wid] = a; sb[wid] = b; }
    __syncthreads();
    if (threadIdx.x == 0) {
        for (int w = 1; w < 4; ++w) { a += sa[w]; b += sb[w]; }
    }
}

__device__ __forceinline__ float sigm(float y) {
    return 1.f / (1.f + __expf(-(0.05f - y) * 20.f));
}

__global__ __launch_bounds__(256) void fused_kernel(
        const float* __restrict__ pred, const float* __restrict__ targ,
        const float* __restrict__ jp, double2* __restrict__ parts) {

    if (blockIdx.x < FOOT_BLOCKS) {
        // ---------------- foot-contact loss: one block per (b, foot) ----------
        const int FI[4] = {7, 8, 10, 11};
        const int bf = blockIdx.x;
        const int b  = bf >> 2;
        const int j  = FI[bf & 3];
        const float* __restrict__ xrow = jp + ((size_t)(b * JJ + j) * 3) * TT;
        const float* __restrict__ yrow = xrow + TT;
        const float* __restrict__ zrow = xrow + 2 * TT;
        const float4* __restrict__ x4 = reinterpret_cast<const float4*>(xrow);
        const float4* __restrict__ y4 = reinterpret_cast<const float4*>(yrow);
        const float4* __restrict__ z4 = reinterpret_cast<const float4*>(zrow);

        float lsum = 0.f, csum = 0.f;
        #pragma unroll
        for (int cc = 0; cc < 2; ++cc) {
            const int c = threadIdx.x + cc * 256;         // chunk: t in [4c, 4c+4)
            const float4 xv = x4[c], yv = y4[c], zv = z4[c];
            float x0 = 0.f, y0 = 0.f, z0 = 0.f;
            if (c > 0) { x0 = xrow[4*c-1]; y0 = yrow[4*c-1]; z0 = zrow[4*c-1]; }
            const float w0 = sigm(y0),  w1 = sigm(yv.x), w2 = sigm(yv.y),
                        w3 = sigm(yv.z), w4 = sigm(yv.w);
            auto term = [&](float x1, float xp, float z1, float zp,
                            float wa, float wb) {
                const float cw = 0.5f * (wa + wb);
                const float vx = x1 - xp, vz = z1 - zp;
                lsum += (vx * vx + vz * vz) * cw;
                csum += cw;
            };
            if (c > 0) term(xv.x, x0, zv.x, z0, w1, w0);
            term(xv.y, xv.x, zv.y, zv.x, w2, w1);
            term(xv.z, xv.y, zv.z, zv.y, w3, w2);
            term(xv.w, xv.z, zv.w, zv.z, w4, w3);
        }
        block_reduce2f(lsum, csum);
        if (threadIdx.x == 0)
            parts[blockIdx.x] = make_double2((double)lsum, (double)csum);
    } else {
        // ---- recon + vel: 4 chunks/thread, boundary via LDS exchange ---------
        // vmem per thread: 8 dwordx4 (+8 exec-masked dwords on thread 0 only)
        const int gtid = (blockIdx.x - FOOT_BLOCKS) * 256 + threadIdx.x;
        const float4* __restrict__ pred4 = reinterpret_cast<const float4*>(pred);
        const float4* __restrict__ targ4 = reinterpret_cast<const float4*>(targ);
        // chunk c_k = gtid + k*NRT; NRT%512==0 -> row-start iff gtid%512==0
        const bool hasb = (gtid & 511) != 0;

        float4 P[4], G[4];
        #pragma unroll
        for (int k = 0; k < 4; ++k) {
            const int c = gtid + k * NRT;
            P[k] = pred4[c];
            G[k] = targ4[c];
        }
        // block-first thread patches its boundary from global (masked, issued
        // before the barrier so it overlaps the LDS exchange)
        float pm[4] = {0.f,0.f,0.f,0.f}, gm[4] = {0.f,0.f,0.f,0.f};
        if (threadIdx.x == 0 && hasb) {
            #pragma unroll
            for (int k = 0; k < 4; ++k) {
                const int e = 4 * (gtid + k * NRT);
                pm[k] = pred[e - 1];
                gm[k] = targ[e - 1];
            }
        }

        float recon = 0.f, vel = 0.f;
        float d0v[4], d3v[4];
        #pragma unroll
        for (int k = 0; k < 4; ++k) {
            const float dx = P[k].x - G[k].x, dy = P[k].y - G[k].y,
                        dz = P[k].z - G[k].z, dw = P[k].w - G[k].w;
            recon += dx*dx + dy*dy + dz*dz + dw*dw;
            const float e01 = dy - dx, e12 = dz - dy, e23 = dw - dz;
            vel += e01*e01 + e12*e12 + e23*e23;
            d0v[k] = dx; d3v[k] = dw;
        }

        __shared__ float4 sd3[256];
        sd3[threadIdx.x] = make_float4(d3v[0], d3v[1], d3v[2], d3v[3]);
        __syncthreads();
        float4 prev;
        if (threadIdx.x > 0) prev = sd3[threadIdx.x - 1];
        else prev = make_float4(pm[0]-gm[0], pm[1]-gm[1], pm[2]-gm[2], pm[3]-gm[3]);

        if (hasb) {
            float b;
            b = d0v[0] - prev.x; vel += b*b;
            b = d0v[1] - prev.y; vel += b*b;
            b = d0v[2] - prev.z; vel += b*b;
            b = d0v[3] - prev.w; vel += b*b;
        }

        block_reduce2f(recon, vel);
        if (threadIdx.x == 0)
            parts[blockIdx.x] = make_double2((double)recon, (double)vel);
    }
}

// One block reduces all 4864 double2 partials and writes the scalar loss.
__global__ __launch_bounds__(256) void finalize_kernel(
        const double2* __restrict__ parts, float* __restrict__ out) {
    double fl = 0.0, fc = 0.0, rc = 0.0, vl = 0.0;
    for (int i = threadIdx.x; i < NBLK; i += 256) {
        const double2 v = parts[i];
        if (i < FOOT_BLOCKS) { fl += v.x; fc += v.y; }
        else                 { rc += v.x; vl += v.y; }
    }
    #pragma unroll
    for (int off = 32; off > 0; off >>= 1) {
        rc += __shfl_down(rc, off);
        vl += __shfl_down(vl, off);
        fl += __shfl_down(fl, off);
        fc += __shfl_down(fc, off);
    }
    __shared__ double s4[4][4];
    const int lane = threadIdx.x & 63, wid = threadIdx.x >> 6;
    if (lane == 0) { s4[wid][0]=rc; s4[wid][1]=vl; s4[wid][2]=fl; s4[wid][3]=fc; }
    __syncthreads();
    if (threadIdx.x == 0) {
        for (int w = 1; w < 4; ++w) {
            rc += s4[w][0]; vl += s4[w][1]; fl += s4[w][2]; fc += s4[w][3];
        }
        const double r = rc / (double)NELEM;
        const double v = vl / (double)NVEL;
        const double f = fl / (fc + 1e-8);
        out[0] = (float)(r + 0.2 * v + 0.1 * f);
    }
}

extern "C" void kernel_launch(void* const* d_in, const int* in_sizes, int n_in,
                              void* d_out, int out_size, void* d_ws, size_t ws_size,
                              hipStream_t stream) {
    const float* pred = (const float*)d_in[0];
    const float* targ = (const float*)d_in[1];
    const float* jp   = (const float*)d_in[2];
    float* out     = (float*)d_out;
    double2* parts = (double2*)d_ws;

    fused_kernel<<<NBLK, 256, 0, stream>>>(pred, targ, jp, parts);
    finalize_kernel<<<1, 256, 0, stream>>>(parts, out);
}

// Round 8
// 189.273 us; speedup vs baseline: 1.0076x; 1.0076x over previous
//
#include <hip/hip_runtime.h>

#define BB 64
#define JJ 24
#define TT 2048
#define NELEM (BB*JJ*6*TT)              // 18,874,368 floats
#define NVEL  ((long long)BB*JJ*6*(TT-1))
#define FOOT_BLOCKS 256
#define RGRID 2048
#define NTH (RGRID*256)                 // 524,288 recon threads
#define NC4 (NELEM/4)                   // 4,718,592 float4 chunks per tensor
#define ITERS 9                         // NC4 / NTH exactly
#define NBLK (FOOT_BLOCKS + RGRID)      // 2304 partial slots

__device__ __forceinline__ void block_reduce2f(float& a, float& b) {
    #pragma unroll
    for (int off = 32; off > 0; off >>= 1) {
        a += __shfl_down(a, off);
        b += __shfl_down(b, off);
    }
    __shared__ float sa[4], sb[4];
    const int lane = threadIdx.x & 63;
    const int wid  = threadIdx.x >> 6;
    if (lane == 0) { sa[wid] = a; sb[wid] = b; }
    __syncthreads();
    if (threadIdx.x == 0) {
        for (int w = 1; w < 4; ++w) { a += sa[w]; b += sb[w]; }
    }
}

__device__ __forceinline__ float sigm(float y) {
    return 1.f / (1.f + __expf(-(0.05f - y) * 20.f));
}

__global__ __launch_bounds__(256) void fused_kernel(
        const float* __restrict__ pred, const float* __restrict__ targ,
        const float* __restrict__ jp, double2* __restrict__ parts) {

    if (blockIdx.x < FOOT_BLOCKS) {
        // ---------------- foot-contact loss: one block per (b, foot) ----------
        const int FI[4] = {7, 8, 10, 11};
        const int bf = blockIdx.x;
        const int b  = bf >> 2;
        const int j  = FI[bf & 3];
        const float* __restrict__ xrow = jp + ((size_t)(b * JJ + j) * 3) * TT;
        const float* __restrict__ yrow = xrow + TT;
        const float* __restrict__ zrow = xrow + 2 * TT;
        const float4* __restrict__ x4 = reinterpret_cast<const float4*>(xrow);
        const float4* __restrict__ y4 = reinterpret_cast<const float4*>(yrow);
        const float4* __restrict__ z4 = reinterpret_cast<const float4*>(zrow);

        float lsum = 0.f, csum = 0.f;
        #pragma unroll
        for (int cc = 0; cc < 2; ++cc) {
            const int c = threadIdx.x + cc * 256;         // chunk: t in [4c, 4c+4)
            const float4 xv = x4[c], yv = y4[c], zv = z4[c];
            float x0 = 0.f, y0 = 0.f, z0 = 0.f;
            if (c > 0) { x0 = xrow[4*c-1]; y0 = yrow[4*c-1]; z0 = zrow[4*c-1]; }
            const float w0 = sigm(y0),  w1 = sigm(yv.x), w2 = sigm(yv.y),
                        w3 = sigm(yv.z), w4 = sigm(yv.w);
            auto term = [&](float x1, float xp, float z1, float zp,
                            float wa, float wb) {
                const float cw = 0.5f * (wa + wb);
                const float vx = x1 - xp, vz = z1 - zp;
                lsum += (vx * vx + vz * vz) * cw;
                csum += cw;
            };
            if (c > 0) term(xv.x, x0, zv.x, z0, w1, w0);
            term(xv.y, xv.x, zv.y, zv.x, w2, w1);
            term(xv.z, xv.y, zv.z, zv.y, w3, w2);
            term(xv.w, xv.z, zv.w, zv.z, w4, w3);
        }
        block_reduce2f(lsum, csum);
        if (threadIdx.x == 0)
            parts[blockIdx.x] = make_double2((double)lsum, (double)csum);
    } else {
        // ---- recon + vel: 9-iter software-pipelined grid-stride loop ---------
        const int t = (blockIdx.x - FOOT_BLOCKS) * 256 + threadIdx.x;
        const float4* __restrict__ pred4 = reinterpret_cast<const float4*>(pred);
        const float4* __restrict__ targ4 = reinterpret_cast<const float4*>(targ);
        // chunk c_k = t + k*NTH; NTH % 512 == 0 -> row-start iff (t & 511)==0
        const bool hasb  = (t & 511) != 0;
        const bool lead  = (threadIdx.x & 63) == 0;   // wave lane 0 patches via global

        // prologue: loads for iter 0
        float4 P0 = pred4[t], G0 = targ4[t];
        float pmg0 = 0.f;
        if (lead && hasb) pmg0 = pred[4*t - 1] - targ[4*t - 1];

        float recon = 0.f, vel = 0.f;
        #pragma unroll 1
        for (int k = 0; k < ITERS; ++k) {
            // prefetch iter k+1 (in flight during this iteration's compute)
            float4 P1, G1;
            float pmg1 = 0.f;
            if (k + 1 < ITERS) {
                const int c = t + (k + 1) * NTH;
                P1 = pred4[c];
                G1 = targ4[c];
                if (lead && hasb) pmg1 = pred[4*c - 1] - targ[4*c - 1];
            }

            const float d0 = P0.x - G0.x, d1 = P0.y - G0.y,
                        d2 = P0.z - G0.z, d3 = P0.w - G0.w;
            recon += d0*d0 + d1*d1 + d2*d2 + d3*d3;
            const float e01 = d1 - d0, e12 = d2 - d1, e23 = d3 - d2;
            vel += e01*e01 + e12*e12 + e23*e23;

            float prev = __shfl_up(d3, 1);
            if (lead) prev = pmg0;
            if (hasb) { const float b0 = d0 - prev; vel += b0 * b0; }

            P0 = P1; G0 = G1; pmg0 = pmg1;
        }

        block_reduce2f(recon, vel);
        if (threadIdx.x == 0)
            parts[blockIdx.x] = make_double2((double)recon, (double)vel);
    }
}

// One block reduces all 2304 double2 partials and writes the scalar loss.
__global__ __launch_bounds__(256) void finalize_kernel(
        const double2* __restrict__ parts, float* __restrict__ out) {
    double fl = 0.0, fc = 0.0, rc = 0.0, vl = 0.0;
    for (int i = threadIdx.x; i < NBLK; i += 256) {
        const double2 v = parts[i];
        if (i < FOOT_BLOCKS) { fl += v.x; fc += v.y; }
        else                 { rc += v.x; vl += v.y; }
    }
    #pragma unroll
    for (int off = 32; off > 0; off >>= 1) {
        rc += __shfl_down(rc, off);
        vl += __shfl_down(vl, off);
        fl += __shfl_down(fl, off);
        fc += __shfl_down(fc, off);
    }
    __shared__ double s4[4][4];
    const int lane = threadIdx.x & 63, wid = threadIdx.x >> 6;
    if (lane == 0) { s4[wid][0]=rc; s4[wid][1]=vl; s4[wid][2]=fl; s4[wid][3]=fc; }
    __syncthreads();
    if (threadIdx.x == 0) {
        for (int w = 1; w < 4; ++w) {
            rc += s4[w][0]; vl += s4[w][1]; fl += s4[w][2]; fc += s4[w][3];
        }
        const double r = rc / (double)NELEM;
        const double v = vl / (double)NVEL;
        const double f = fl / (fc + 1e-8);
        out[0] = (float)(r + 0.2 * v + 0.1 * f);
    }
}

extern "C" void kernel_launch(void* const* d_in, const int* in_sizes, int n_in,
                              void* d_out, int out_size, void* d_ws, size_t ws_size,
                              hipStream_t stream) {
    const float* pred = (const float*)d_in[0];
    const float* targ = (const float*)d_in[1];
    const float* jp   = (const float*)d_in[2];
    float* out     = (float*)d_out;
    double2* parts = (double2*)d_ws;

    fused_kernel<<<NBLK, 256, 0, stream>>>(pred, targ, jp, parts);
    finalize_kernel<<<1, 256, 0, stream>>>(parts, out);
}

// Round 9
// 187.554 us; speedup vs baseline: 1.0169x; 1.0092x over previous
//
#include <hip/hip_runtime.h>

#define BB 64
#define JJ 24
#define TT 2048
#define NELEM (BB*JJ*6*TT)              // 18,874,368 floats
#define NVEL  ((long long)BB*JJ*6*(TT-1))
#define RGRID 2048                      // uniform grid: 8 blocks/CU exactly
#define NTH (RGRID*256)                 // 524,288 threads
#define ITERS 9                         // (NELEM/4) / NTH exactly
#define SEGT 256                        // foot timesteps per block (2048/8)

__device__ __forceinline__ float sigm(float y) {
    return 1.f / (1.f + __expf(-(0.05f - y) * 20.f));
}

// Reduce four per-thread floats to block totals (wave butterfly + LDS).
__device__ __forceinline__ void block_reduce4f(float& a, float& b,
                                               float& c, float& d) {
    #pragma unroll
    for (int off = 32; off > 0; off >>= 1) {
        a += __shfl_down(a, off);
        b += __shfl_down(b, off);
        c += __shfl_down(c, off);
        d += __shfl_down(d, off);
    }
    __shared__ float s[4][4];
    const int lane = threadIdx.x & 63;
    const int wid  = threadIdx.x >> 6;
    if (lane == 0) { s[wid][0]=a; s[wid][1]=b; s[wid][2]=c; s[wid][3]=d; }
    __syncthreads();
    if (threadIdx.x == 0) {
        for (int w = 1; w < 4; ++w) {
            a += s[w][0]; b += s[w][1]; c += s[w][2]; d += s[w][3];
        }
    }
}

// parts[b] = (recon, vel, foot_l, foot_c) partials for block b.
__global__ __launch_bounds__(256) void fused_kernel(
        const float* __restrict__ pred, const float* __restrict__ targ,
        const float* __restrict__ jp, double4* __restrict__ parts) {

    const int t = blockIdx.x * 256 + threadIdx.x;
    const float4* __restrict__ pred4 = reinterpret_cast<const float4*>(pred);
    const float4* __restrict__ targ4 = reinterpret_cast<const float4*>(targ);
    const bool hasb = (t & 511) != 0;        // chunk starts a T-row iff t%512==0
    const bool lead = (threadIdx.x & 63) == 0;

    // ---------------- foot segment first (loads overlap recon stream) --------
    // block g covers (b,foot) pair g>>3, timesteps [ (g&7)*SEGT , +SEGT ).
    float footl = 0.f, footc = 0.f;
    {
        const int FI[4] = {7, 8, 10, 11};
        const int pair = blockIdx.x >> 3;        // 0..255
        const int seg  = blockIdx.x & 7;
        const int b    = pair >> 2;
        const int j    = FI[pair & 3];
        const float* __restrict__ xrow = jp + ((size_t)(b * JJ + j) * 3) * TT;
        const float* __restrict__ yrow = xrow + TT;
        const float* __restrict__ zrow = xrow + 2 * TT;
        const int tt = seg * SEGT + threadIdx.x; // global timestep, one per thread
        if (tt >= 1) {
            const float x1 = xrow[tt], x0 = xrow[tt - 1];
            const float y1 = yrow[tt], y0 = yrow[tt - 1];
            const float z1 = zrow[tt], z0 = zrow[tt - 1];
            const float cw = 0.5f * (sigm(y1) + sigm(y0));
            const float vx = x1 - x0, vz = z1 - z0;
            footl = (vx * vx + vz * vz) * cw;
            footc = cw;
        }
    }

    // ---------------- recon + vel: 9 chunks/thread ---------------------------
    float recon = 0.f, vel = 0.f;
    #pragma unroll 3
    for (int k = 0; k < ITERS; ++k) {
        const int c = t + k * NTH;
        const float4 P = pred4[c];
        const float4 G = targ4[c];
        float pmg = 0.f;
        if (lead && hasb) pmg = pred[4*c - 1] - targ[4*c - 1];

        const float d0 = P.x - G.x, d1 = P.y - G.y,
                    d2 = P.z - G.z, d3 = P.w - G.w;
        recon += d0*d0 + d1*d1 + d2*d2 + d3*d3;
        const float e01 = d1 - d0, e12 = d2 - d1, e23 = d3 - d2;
        vel += e01*e01 + e12*e12 + e23*e23;

        float prev = __shfl_up(d3, 1);
        if (lead) prev = pmg;
        if (hasb) { const float b0 = d0 - prev; vel += b0 * b0; }
    }

    block_reduce4f(recon, vel, footl, footc);
    if (threadIdx.x == 0)
        parts[blockIdx.x] = make_double4((double)recon, (double)vel,
                                         (double)footl, (double)footc);
}

// One block reduces all RGRID double4 partials and writes the scalar loss.
__global__ __launch_bounds__(256) void finalize_kernel(
        const double4* __restrict__ parts, float* __restrict__ out) {
    double rc = 0.0, vl = 0.0, fl = 0.0, fc = 0.0;
    for (int i = threadIdx.x; i < RGRID; i += 256) {
        const double4 v = parts[i];
        rc += v.x; vl += v.y; fl += v.z; fc += v.w;
    }
    #pragma unroll
    for (int off = 32; off > 0; off >>= 1) {
        rc += __shfl_down(rc, off);
        vl += __shfl_down(vl, off);
        fl += __shfl_down(fl, off);
        fc += __shfl_down(fc, off);
    }
    __shared__ double s4[4][4];
    const int lane = threadIdx.x & 63, wid = threadIdx.x >> 6;
    if (lane == 0) { s4[wid][0]=rc; s4[wid][1]=vl; s4[wid][2]=fl; s4[wid][3]=fc; }
    __syncthreads();
    if (threadIdx.x == 0) {
        for (int w = 1; w < 4; ++w) {
            rc += s4[w][0]; vl += s4[w][1]; fl += s4[w][2]; fc += s4[w][3];
        }
        const double r = rc / (double)NELEM;
        const double v = vl / (double)NVEL;
        const double f = fl / (fc + 1e-8);
        out[0] = (float)(r + 0.2 * v + 0.1 * f);
    }
}

extern "C" void kernel_launch(void* const* d_in, const int* in_sizes, int n_in,
                              void* d_out, int out_size, void* d_ws, size_t ws_size,
                              hipStream_t stream) {
    const float* pred = (const float*)d_in[0];
    const float* targ = (const float*)d_in[1];
    const float* jp   = (const float*)d_in[2];
    float* out     = (float*)d_out;
    double4* parts = (double4*)d_ws;

    fused_kernel<<<RGRID, 256, 0, stream>>>(pred, targ, jp, parts);
    finalize_kernel<<<1, 256, 0, stream>>>(parts, out);
}